// Round 1
// baseline (39772.409 us; speedup 1.0000x reference)
//
#include <hip/hip_runtime.h>
#include <stdint.h>

// DSNN bit-exact fp32. Locked-in facts:
//  - Ref is k-ascending single-accumulator fma (R1/R4/R5/R6 absmax 0.0); any
//    reorder/reprecision flips spikes chaotically (R2: 511). Dense fmaf with
//    spike in {0.0,1.0} is bitwise == conditional add. No MFMA (no fp32 MFMA).
//  - Pipe model per CU-j (16 waves, 1 block/CU): VALU 128 cyc, TCP (W dwordx2,
//    8 lines/wave) 128 cyc, LDS was 2x ds_read_b128 broadcast/wave ~ 9.5 cyc
//    each -> ~300 cyc effective -> LDS-issue-bound (measured 33.0 ms vs 13.9 ms
//    VALU floor).
//  - R8 (this): spikes packed as f16 {0.0h,1.0h} -> 8 broadcast rows in ONE
//    ds_read_b128; consumed via v_fma_mix_f32 (f16 src0 converts exactly ->
//    bitwise == fmaf(s,w,acc)). LDS gemm reads halve; VALU/TCP unchanged.
//    x-stage gemm (real-valued x) keeps the f32 path. f16 spike view aliases
//    the x-stage buffer (40960 B <= 73728 B), LDS footprint unchanged.

typedef __attribute__((ext_vector_type(2))) float f32x2;
typedef __attribute__((ext_vector_type(4))) float f32x4;

#define ALPHA 0.9f
#define BETA 0.85f
#define NSTEPS 127
#define WGT 1024
#define ROWS 32
#define CPAD 36     // x-stage f32 col stride (floats): 32 rows + 4 pad
#define SPH 20      // packed-spike col stride (dwords): 16 dw (32 f16 rows) + 4 pad = 80 B (16B mult)
#define HPAD 516    // h0buf row stride (floats)

// Update forms verbatim from R1/R4 (bit-exact-verified vs np reference),
// spike output as bool for f16 packing.
#define LIF_L0(M, H, B) { float _m = BETA * (M) + (H); \
    (B) = (_m - 1.0f) > 0.0f; (M) = (B) ? 0.0f : _m; }
#define LIF_MID(S, M, A, B) { (S) = ALPHA * (S) + (A); \
    float _m = BETA * (M) + (S); (B) = (_m - 1.0f) > 0.0f; \
    (M) = (B) ? 0.0f : _m; }
#define LIF_OUT(S, M, A) { (S) = ALPHA * (S) + (A); (M) = BETA * (M) + (S); }

// f16 1.0 = 0x3C00; pack two row-spikes into one dword (lo = even row, hi = odd).
#define PACK2(L, H) ((((L)) ? 0x3C00u : 0u) | (((H)) ? 0x3C000000u : 0u))

// f32 fma taking the f16 multiplicand from lo/hi half of dword S.
// v_fma_mix_f32 converts the f16 source to f32 exactly, then does a normal
// f32 fma -> bitwise identical to fmaf((float)s, w, acc) for s in {0,1}.
#define FMIX_LO(A, S, W) asm("v_fma_mix_f32 %0, %1, %2, %0 op_sel:[0,0,0] op_sel_hi:[1,0,0]" \
    : "+v"(A) : "v"(S), "v"(W))
#define FMIX_HI(A, S, W) asm("v_fma_mix_f32 %0, %1, %2, %0 op_sel:[1,0,0] op_sel_hi:[1,0,0]" \
    : "+v"(A) : "v"(S), "v"(W))

__global__ __launch_bounds__(WGT, 4)
void dsnn_kernel(const float* __restrict__ x,
                 const float* __restrict__ W0,
                 const float* __restrict__ W1,
                 const float* __restrict__ W2,
                 float* __restrict__ out)
{
    __shared__ float spkbuf[512 * CPAD];   // 73728 B; x-stage f32, then f16-packed spikes
    __shared__ float h0buf[ROWS * HPAD];   // 66048 B, [row][col]
    uint32_t* spkh = (uint32_t*)spkbuf;    // packed-spike view: [col][dword], stride SPH

    const int t  = threadIdx.x;
    const int c2 = (t & 255) * 2;          // cols c2, c2+1
    const int g  = (t >> 8) * 8;           // rows g..g+7 (wave-uniform)
    const int gd = g >> 1;                 // dword offset of row-group in a packed col
    const int r0 = blockIdx.x * ROWS;

    // ---- stage x (pos/neg split) into spkbuf [i][row], i = 0..255 ----
    for (int k = t; k < 256 * ROWS; k += WGT) {
        const int i = k >> 5;
        const int r = k & 31;
        const float v = (i < 128) ? x[(size_t)(r0 + r) * 128 + i]
                                  : -x[(size_t)(r0 + r) * 128 + (i - 128)];
        spkbuf[i * CPAD + r] = fmaxf(v, 0.0f);
    }
    __syncthreads();

    float acc[8][2];   // [row r][col cc]

    // f32 gemm over real-valued x (h0 phase only); j ascending (bit-exact order)
    auto gemm_x = [&](const float* Wcol, int K) {
        #pragma unroll 2
        for (int j = 0; j < K; ++j) {
            const float* sb = spkbuf + j * CPAD + g;       // wave-uniform -> broadcast
            const f32x4 sA = *(const f32x4*)(sb);          // rows g..g+3
            const f32x4 sB = *(const f32x4*)(sb + 4);      // rows g+4..g+7
            const f32x2 wv = *(const f32x2*)(Wcol + (size_t)j * 512);
            #pragma unroll
            for (int rr = 0; rr < 4; ++rr) {
                acc[rr][0]     = fmaf(sA[rr], wv.x, acc[rr][0]);
                acc[rr][1]     = fmaf(sA[rr], wv.y, acc[rr][1]);
                acc[4 + rr][0] = fmaf(sB[rr], wv.x, acc[4 + rr][0]);
                acc[4 + rr][1] = fmaf(sB[rr], wv.y, acc[4 + rr][1]);
            }
        }
    };

    // f16-spike gemm: ONE broadcast b128 per wave-j delivers 8 packed rows.
    // dword k of a col = rows 2k (lo), 2k+1 (hi); matches the pack order below.
    auto gemm_h = [&](const float* Wcol, int K) {
        #pragma unroll 2
        for (int j = 0; j < K; ++j) {
            const uint4 sp = *(const uint4*)(spkh + j * SPH + gd);
            const f32x2 wv = *(const f32x2*)(Wcol + (size_t)j * 512);
            FMIX_LO(acc[0][0], sp.x, wv.x); FMIX_LO(acc[0][1], sp.x, wv.y);
            FMIX_HI(acc[1][0], sp.x, wv.x); FMIX_HI(acc[1][1], sp.x, wv.y);
            FMIX_LO(acc[2][0], sp.y, wv.x); FMIX_LO(acc[2][1], sp.y, wv.y);
            FMIX_HI(acc[3][0], sp.y, wv.x); FMIX_HI(acc[3][1], sp.y, wv.y);
            FMIX_LO(acc[4][0], sp.z, wv.x); FMIX_LO(acc[4][1], sp.z, wv.y);
            FMIX_HI(acc[5][0], sp.z, wv.x); FMIX_HI(acc[5][1], sp.z, wv.y);
            FMIX_LO(acc[6][0], sp.w, wv.x); FMIX_LO(acc[6][1], sp.w, wv.y);
            FMIX_HI(acc[7][0], sp.w, wv.x); FMIX_HI(acc[7][1], sp.w, wv.y);
        }
    };

    // ---- h0 = x @ W0 (time-invariant), park in LDS ----
    #pragma unroll
    for (int r = 0; r < 8; ++r) { acc[r][0] = 0.0f; acc[r][1] = 0.0f; }
    gemm_x(W0 + c2, 256);
    #pragma unroll
    for (int r = 0; r < 8; ++r) {
        f32x2 hv = { acc[r][0], acc[r][1] };
        *(f32x2*)(h0buf + (g + r) * HPAD + c2) = hv;
    }
    __syncthreads();   // all x-reads done before spkbuf is reused for packed spikes

    // ---- recurrent state in registers: 5 x 16 = 80 ----
    float m0[8][2], s1[8][2], m1[8][2], s2[8][2], m2[8][2];
    #pragma unroll
    for (int r = 0; r < 8; ++r)
        #pragma unroll
        for (int cc = 0; cc < 2; ++cc) {
            m0[r][cc] = 0.f; s1[r][cc] = 0.f; m1[r][cc] = 0.f;
            s2[r][cc] = 0.f; m2[r][cc] = 0.f;
        }

    for (int step = 0; step < NSTEPS; ++step) {
        // ===== layer 0: m0 = BETA*m0 + h0; spike; reset; packed spikes -> LDS =====
        {
            bool bA[2][4], bB[2][4];   // [cc][rr]: rows g+rr / g+4+rr
            #pragma unroll
            for (int rr = 0; rr < 4; ++rr) {
                const f32x2 hva = *(const f32x2*)(h0buf + (g + rr) * HPAD + c2);
                const f32x2 hvb = *(const f32x2*)(h0buf + (g + 4 + rr) * HPAD + c2);
                LIF_L0(m0[rr][0], hva.x, bA[0][rr]);
                LIF_L0(m0[rr][1], hva.y, bA[1][rr]);
                LIF_L0(m0[4 + rr][0], hvb.x, bB[0][rr]);
                LIF_L0(m0[4 + rr][1], hvb.y, bB[1][rr]);
            }
            #pragma unroll
            for (int cc = 0; cc < 2; ++cc) {
                uint4 pk;
                pk.x = PACK2(bA[cc][0], bA[cc][1]);   // rows g+0, g+1
                pk.y = PACK2(bA[cc][2], bA[cc][3]);   // rows g+2, g+3
                pk.z = PACK2(bB[cc][0], bB[cc][1]);   // rows g+4, g+5
                pk.w = PACK2(bB[cc][2], bB[cc][3]);   // rows g+6, g+7
                *(uint4*)(spkh + (c2 + cc) * SPH + gd) = pk;
            }
        }
        __syncthreads();                       // A: L0 spikes visible

        // ===== layer 1: h1 = spk0 @ W1 =====
        #pragma unroll
        for (int r = 0; r < 8; ++r) { acc[r][0] = 0.0f; acc[r][1] = 0.0f; }
        gemm_h(W1 + c2, 512);
        __syncthreads();                       // B: all reads of L0 spikes done

        {
            bool bA[2][4], bB[2][4];
            #pragma unroll
            for (int rr = 0; rr < 4; ++rr) {
                LIF_MID(s1[rr][0], m1[rr][0], acc[rr][0], bA[0][rr]);
                LIF_MID(s1[rr][1], m1[rr][1], acc[rr][1], bA[1][rr]);
                LIF_MID(s1[4 + rr][0], m1[4 + rr][0], acc[4 + rr][0], bB[0][rr]);
                LIF_MID(s1[4 + rr][1], m1[4 + rr][1], acc[4 + rr][1], bB[1][rr]);
            }
            #pragma unroll
            for (int cc = 0; cc < 2; ++cc) {
                uint4 pk;
                pk.x = PACK2(bA[cc][0], bA[cc][1]);
                pk.y = PACK2(bA[cc][2], bA[cc][3]);
                pk.z = PACK2(bB[cc][0], bB[cc][1]);
                pk.w = PACK2(bB[cc][2], bB[cc][3]);
                *(uint4*)(spkh + (c2 + cc) * SPH + gd) = pk;
            }
        }
        __syncthreads();                       // C: L1 spikes visible

        // ===== layer 2: h2 = spk1 @ W2; s2,m2 update; no reset =====
        #pragma unroll
        for (int r = 0; r < 8; ++r) { acc[r][0] = 0.0f; acc[r][1] = 0.0f; }
        gemm_h(W2 + c2, 512);
        #pragma unroll
        for (int r = 0; r < 8; ++r) {
            LIF_OUT(s2[r][0], m2[r][0], acc[r][0]);
            LIF_OUT(s2[r][1], m2[r][1], acc[r][1]);
        }
        __syncthreads();                       // D: L1-spike reads done before next L0 write
    }

    // ---- write final m2 ----
    #pragma unroll
    for (int r = 0; r < 8; ++r) {
        f32x2 ov = { m2[r][0], m2[r][1] };
        *(f32x2*)(out + (size_t)(r0 + g + r) * 512 + c2) = ov;
    }
}

extern "C" void kernel_launch(void* const* d_in, const int* in_sizes, int n_in,
                              void* d_out, int out_size, void* d_ws, size_t ws_size,
                              hipStream_t stream) {
    const float* inputs = (const float*)d_in[0];   // 16384 x 128
    const float* W0     = (const float*)d_in[1];   // 256 x 512
    const float* W1     = (const float*)d_in[2];   // 512 x 512
    const float* W2     = (const float*)d_in[3];   // 512 x 512
    float* out          = (float*)d_out;           // 16384 x 512

    dim3 grid(16384 / ROWS);     // 512 workgroups, 32 rows each
    dim3 block(WGT);
    dsnn_kernel<<<grid, block, 0, stream>>>(inputs, W0, W1, W2, out);
}